// Round 7
// baseline (416.534 us; speedup 1.0000x reference)
//
#include <hip/hip_runtime.h>
#include <math.h>

#define NN 100000
#define NE 1600000
#define F_IN 128
#define C 128           // N_HEADS * F_OUT
#define NEG_SLOPE 0.2f
#define SCAN_NB ((NN + 1023) / 1024)   // 98
#define PROJ_NB ((NN + 63) / 64)       // 1563
#define HIST_NB ((NE + 255) / 256)     // 6250

typedef __attribute__((ext_vector_type(8))) short short8;    // 8 x bf16
typedef __attribute__((ext_vector_type(4))) float f32x4;
typedef __attribute__((ext_vector_type(4))) float floatx4;
typedef __attribute__((ext_vector_type(4))) unsigned short ushortx4;

static __device__ __forceinline__ unsigned short f2bf(float f) {
    unsigned int u = __float_as_uint(f);
    unsigned int r = (u + 0x7fff + ((u >> 16) & 1)) >> 16;  // RNE
    return (unsigned short)r;
}
static __device__ __forceinline__ float bf2f(unsigned short h) {
    return __uint_as_float((unsigned int)h << 16);
}

// ---------------------------------------------------------------------------
// Btf: fragment-major B for mfma_f32_16x16x32_bf16.
// Btf[((nt*4+kc)*64 + lane)*8 + j] = B[k][n], n = nt*16+(lane&15),
//   k = kc*32 + (lane>>4)*8 + j.  n<128 -> W, else W_res.
// ---------------------------------------------------------------------------
__global__ __launch_bounds__(256)
void wconv_kernel(const float* __restrict__ W,
                  const float* __restrict__ Wr,
                  unsigned short* __restrict__ Btf)
{
    int g = blockIdx.x * 256 + threadIdx.x;   // 0..4095
    int nt = g >> 8;
    int kc = (g >> 6) & 3;
    int l  = g & 63;
    int n  = nt * 16 + (l & 15);
    int kb = kc * 32 + (l >> 4) * 8;
    unsigned short v[8];
    #pragma unroll
    for (int j = 0; j < 8; ++j) {
        int k = kb + j;
        float f = (n < 128) ? W[(size_t)k * 128 + n] : Wr[(size_t)k * 128 + (n - 128)];
        v[j] = f2bf(f);
    }
    *(short8*)&Btf[(size_t)g * 8] = *(short8*)v;
}

// ---------------------------------------------------------------------------
// Fat kernel: blocks [0,PROJ_NB) = projection GEMM; blocks >= PROJ_NB = hist.
// proj: x(bf16)->xb, res(bf16)->resb, logits coalesced via LDS stage.
// launch_bounds(256,2): generous register budget -> no scratch spill.
// ---------------------------------------------------------------------------
__global__ __launch_bounds__(256, 2)
void proj_hist_kernel(const float* __restrict__ feat,
                      const unsigned short* __restrict__ Btf,
                      const float* __restrict__ att_src,
                      const float* __restrict__ att_dst,
                      const int* __restrict__ dst,
                      unsigned short* __restrict__ xb,
                      unsigned short* __restrict__ resb,
                      float* __restrict__ a_s,
                      float* __restrict__ a_d,
                      int* __restrict__ deg,
                      int* __restrict__ rank)
{
    __shared__ __align__(16) char smem[17408];
    __shared__ float s_as[64][4];
    __shared__ float s_ad[64][4];
    const int tid = threadIdx.x;

    if (blockIdx.x >= PROJ_NB) {          // ---- histogram part ----
        int e = (blockIdx.x - PROJ_NB) * 256 + tid;
        if (e < NE) rank[e] = atomicAdd(&deg[dst[e]], 1);
        return;
    }

    unsigned short* As = (unsigned short*)smem;   // [64][136]
    const int base = blockIdx.x * 64;

    #pragma unroll
    for (int it = 0; it < 8; ++it) {
        int idx = it * 256 + tid;
        int row = idx >> 5;
        int c4  = idx & 31;
        int n = base + row;
        if (n < NN) {
            floatx4 f = *(const floatx4*)&feat[(size_t)n * F_IN + c4 * 4];
            ushortx4 h;
            h.x = f2bf(f.x); h.y = f2bf(f.y); h.z = f2bf(f.z); h.w = f2bf(f.w);
            *(ushortx4*)&As[row * 136 + c4 * 4] = h;
        }
    }
    __syncthreads();

    const int l = tid & 63;
    const int w = tid >> 6;
    const int quad = l >> 4;
    const int lo16 = l & 15;

    short8 af[4];
    const int arow = w * 16 + lo16;
    #pragma unroll
    for (int kc = 0; kc < 4; ++kc)
        af[kc] = *(const short8*)&As[arow * 136 + kc * 32 + quad * 8];
    // No barrier: each wave's T region overlays its OWN A rows.

    f32x4 acc[16];
    #pragma unroll
    for (int nt = 0; nt < 16; ++nt) acc[nt] = (f32x4){0.f, 0.f, 0.f, 0.f};

    #pragma unroll 2
    for (int nt = 0; nt < 16; ++nt) {
        const unsigned short* bp = &Btf[(size_t)(nt * 4) * 512 + (l << 3)];
        short8 b0 = *(const short8*)&bp[0];
        short8 b1 = *(const short8*)&bp[512];
        short8 b2 = *(const short8*)&bp[1024];
        short8 b3 = *(const short8*)&bp[1536];
        acc[nt] = __builtin_amdgcn_mfma_f32_16x16x32_bf16(af[0], b0, acc[nt], 0, 0, 0);
        acc[nt] = __builtin_amdgcn_mfma_f32_16x16x32_bf16(af[1], b1, acc[nt], 0, 0, 0);
        acc[nt] = __builtin_amdgcn_mfma_f32_16x16x32_bf16(af[2], b2, acc[nt], 0, 0, 0);
        acc[nt] = __builtin_amdgcn_mfma_f32_16x16x32_bf16(af[3], b3, acc[nt], 0, 0, 0);
    }

    float* T2 = (float*)smem + w * (16 * 68);   // wave-private [16][68]
    const int g  = l >> 4;          // row group within half-tile read
    const int cf = (l & 15) * 4;    // col within 64-col half

    // ---- x passes (nt 0..7) + logits to LDS ----
    #pragma unroll
    for (int p = 0; p < 2; ++p) {
        #pragma unroll
        for (int ntl = 0; ntl < 4; ++ntl) {
            int nt = p * 4 + ntl;
            #pragma unroll
            for (int r = 0; r < 4; ++r)
                T2[(quad * 4 + r) * 68 + ntl * 16 + lo16] = acc[nt][r];
        }
        floatx4 ws4 = *(const floatx4*)&att_src[p * 64 + cf];
        floatx4 wd4 = *(const floatx4*)&att_dst[p * 64 + cf];
        float ps[4], pd[4];
        #pragma unroll
        for (int it = 0; it < 4; ++it) {
            int row = it * 4 + g;
            floatx4 v = *(floatx4*)&T2[row * 68 + cf];
            int node = base + w * 16 + row;
            ushortx4 hh;
            hh.x = f2bf(v.x); hh.y = f2bf(v.y); hh.z = f2bf(v.z); hh.w = f2bf(v.w);
            if (node < NN)
                __builtin_nontemporal_store(hh,
                    (ushortx4*)&xb[(size_t)node * C + p * 64 + cf]);
            ps[it] = v.x * ws4.x + v.y * ws4.y + v.z * ws4.z + v.w * ws4.w;
            pd[it] = v.x * wd4.x + v.y * wd4.y + v.z * wd4.z + v.w * wd4.w;
        }
        #pragma unroll
        for (int it = 0; it < 4; ++it) {
            #pragma unroll
            for (int d = 1; d < 8; d <<= 1) {
                ps[it] += __shfl_xor(ps[it], d, 64);
                pd[it] += __shfl_xor(pd[it], d, 64);
            }
        }
        if ((l & 7) == 0) {
            int hh = p * 2 + ((l & 15) >> 3);
            #pragma unroll
            for (int it = 0; it < 4; ++it) {
                int lr = w * 16 + it * 4 + g;
                s_as[lr][hh] = ps[it];
                s_ad[lr][hh] = pd[it];
            }
        }
    }

    // ---- res passes (nt 8..15), bf16 -> resb ----
    #pragma unroll
    for (int p = 0; p < 2; ++p) {
        #pragma unroll
        for (int ntl = 0; ntl < 4; ++ntl) {
            int nt = 8 + p * 4 + ntl;
            #pragma unroll
            for (int r = 0; r < 4; ++r)
                T2[(quad * 4 + r) * 68 + ntl * 16 + lo16] = acc[nt][r];
        }
        #pragma unroll
        for (int it = 0; it < 4; ++it) {
            int row = it * 4 + g;
            floatx4 v = *(floatx4*)&T2[row * 68 + cf];
            int node = base + w * 16 + row;
            ushortx4 hh;
            hh.x = f2bf(v.x); hh.y = f2bf(v.y); hh.z = f2bf(v.z); hh.w = f2bf(v.w);
            if (node < NN)
                __builtin_nontemporal_store(hh,
                    (ushortx4*)&resb[(size_t)node * C + p * 64 + cf]);
        }
    }

    // ---- coalesced logits store: one contiguous 1KB store per array ----
    __syncthreads();
    int idx = blockIdx.x * 256 + tid;   // = base*4 + tid
    if (idx < NN * 4) {
        a_s[idx] = ((float*)s_as)[tid];
        a_d[idx] = ((float*)s_ad)[tid];
    }
}

// ---------------------------------------------------------------------------
// multi-block exclusive scan
// ---------------------------------------------------------------------------
__global__ __launch_bounds__(1024)
void scan1_kernel(const int* __restrict__ deg, int* __restrict__ row_ptr,
                  int* __restrict__ bsum)
{
    __shared__ int wsum[16];
    const int t = threadIdx.x, lane = t & 63, wid = t >> 6;
    const int i = blockIdx.x * 1024 + t;
    int v0 = (i < NN) ? deg[i] : 0;
    int v = v0;
    #pragma unroll
    for (int off = 1; off < 64; off <<= 1) {
        int u = __shfl_up(v, off, 64);
        if (lane >= off) v += u;
    }
    if (lane == 63) wsum[wid] = v;
    __syncthreads();
    if (t == 0) {
        int run = 0;
        #pragma unroll
        for (int s = 0; s < 16; ++s) { int tmp = wsum[s]; wsum[s] = run; run += tmp; }
        bsum[blockIdx.x] = run;
    }
    __syncthreads();
    if (i < NN) row_ptr[i] = wsum[wid] + (v - v0);
}

__global__ __launch_bounds__(128)
void scan2_kernel(int* __restrict__ bsum)
{
    __shared__ int w0;
    const int t = threadIdx.x, lane = t & 63;
    int v0 = (t < SCAN_NB) ? bsum[t] : 0;
    int v = v0;
    #pragma unroll
    for (int off = 1; off < 64; off <<= 1) {
        int u = __shfl_up(v, off, 64);
        if (lane >= off) v += u;
    }
    if (t == 63) w0 = v;
    __syncthreads();
    int excl = (v - v0) + ((t >= 64) ? w0 : 0);
    if (t < SCAN_NB) bsum[t] = excl;
}

__global__ __launch_bounds__(1024)
void scan3_kernel(int* __restrict__ row_ptr, const int* __restrict__ bsum)
{
    const int i = blockIdx.x * 1024 + threadIdx.x;
    if (i < NN) row_ptr[i] = row_ptr[i] + bsum[i >> 10];
    if (i == 0) row_ptr[NN] = NE;
}

// ---------------------------------------------------------------------------
// scatter: pure load->store, no atomics; nt store avoids L2 line bounce
// ---------------------------------------------------------------------------
__global__ void scatter_kernel(const int* __restrict__ src,
                               const int* __restrict__ dst,
                               const int* __restrict__ rank,
                               const int* __restrict__ row_ptr,
                               int* __restrict__ csr_src)
{
    int e = blockIdx.x * blockDim.x + threadIdx.x;
    if (e < NE)
        __builtin_nontemporal_store(src[e],
            &csr_src[row_ptr[dst[e]] + rank[e]]);
}

// ---------------------------------------------------------------------------
// aggregation: one wave per dst node, single pass, prefetched gather loop.
// out = resb + acc/denom (no out read; nt store).
// ---------------------------------------------------------------------------
__global__ __launch_bounds__(256)
void agg_kernel(const unsigned short* __restrict__ xb,
                const unsigned short* __restrict__ resb,
                const float* __restrict__ a_s,
                const float* __restrict__ a_d,
                const int* __restrict__ row_ptr,
                const int* __restrict__ csr_src,
                float* __restrict__ out)
{
    __shared__ float s_alpha[4][64 * 4];
    __shared__ int   s_srcs[4][64];
    const int tid = threadIdx.x;
    const int w = tid >> 6;
    const int l = tid & 63;
    const int n = blockIdx.x * 4 + w;
    if (n >= NN) return;
    const int r0  = row_ptr[n];
    const int deg = row_ptr[n + 1] - r0;

    const int half = l >> 5;
    const int hl   = l & 31;
    const int h    = hl >> 3;

    if (deg == 0) {                      // out = residual only
        if (half == 0) {
            ushort4 rv = *(const ushort4*)&resb[(size_t)n * C + hl * 4];
            floatx4 o;
            o.x = bf2f(rv.x); o.y = bf2f(rv.y);
            o.z = bf2f(rv.z); o.w = bf2f(rv.w);
            __builtin_nontemporal_store(o, (floatx4*)&out[(size_t)n * C + hl * 4]);
        }
        return;
    }

    const float4 ad4 = *(const float4*)&a_d[n * 4];

    float ax = 0.f, ay = 0.f, az = 0.f, aw = 0.f;
    float dx = 0.f, dy = 0.f, dz = 0.f, dw = 0.f;

    for (int c0 = 0; c0 < deg; c0 += 64) {
        int e = c0 + l;
        int s = 0;
        float4 ex = {0.f, 0.f, 0.f, 0.f};
        if (e < deg) {
            s = csr_src[r0 + e];
            float4 as4 = *(const float4*)&a_s[s * 4];
            float e0 = as4.x + ad4.x, e1 = as4.y + ad4.y;
            float e2 = as4.z + ad4.z, e3 = as4.w + ad4.w;
            e0 = (e0 > 0.f) ? e0 : NEG_SLOPE * e0;
            e1 = (e1 > 0.f) ? e1 : NEG_SLOPE * e1;
            e2 = (e2 > 0.f) ? e2 : NEG_SLOPE * e2;
            e3 = (e3 > 0.f) ? e3 : NEG_SLOPE * e3;
            ex.x = __expf(e0); ex.y = __expf(e1);
            ex.z = __expf(e2); ex.w = __expf(e3);
            dx += ex.x; dy += ex.y; dz += ex.z; dw += ex.w;
        }
        s_srcs[w][l] = s;
        *(float4*)&s_alpha[w][l * 4] = ex;   // wave-private; DS in-order

        int cn = min(64, deg - c0);
        int iters = (cn + 1) >> 1;
        // 1-deep software pipeline on the xb gather
        int   si = s_srcs[w][half];
        float al = s_alpha[w][half * 4 + h];
        ushort4 uv = *(const ushort4*)&xb[(size_t)si * C + hl * 4];
        for (int i = 1; i < iters; ++i) {
            int ii = i * 2 + half;
            int   si2 = s_srcs[w][ii];
            float al2 = s_alpha[w][ii * 4 + h];
            ushort4 uv2 = *(const ushort4*)&xb[(size_t)si2 * C + hl * 4];
            ax = fmaf(al, bf2f(uv.x), ax);
            ay = fmaf(al, bf2f(uv.y), ay);
            az = fmaf(al, bf2f(uv.z), az);
            aw = fmaf(al, bf2f(uv.w), aw);
            al = al2; uv = uv2;
        }
        ax = fmaf(al, bf2f(uv.x), ax);
        ay = fmaf(al, bf2f(uv.y), ay);
        az = fmaf(al, bf2f(uv.z), az);
        aw = fmaf(al, bf2f(uv.w), aw);
    }

    #pragma unroll
    for (int d = 32; d > 0; d >>= 1) {
        dx += __shfl_xor(dx, d, 64);
        dy += __shfl_xor(dy, d, 64);
        dz += __shfl_xor(dz, d, 64);
        dw += __shfl_xor(dw, d, 64);
    }
    float den = (h == 0) ? dx : (h == 1) ? dy : (h == 2) ? dz : dw;
    float inv = 1.f / den;

    ax += __shfl_xor(ax, 32, 64);
    ay += __shfl_xor(ay, 32, 64);
    az += __shfl_xor(az, 32, 64);
    aw += __shfl_xor(aw, 32, 64);

    if (half == 0) {
        ushort4 rv = *(const ushort4*)&resb[(size_t)n * C + hl * 4];
        floatx4 o;
        o.x = bf2f(rv.x) + ax * inv;
        o.y = bf2f(rv.y) + ay * inv;
        o.z = bf2f(rv.z) + az * inv;
        o.w = bf2f(rv.w) + aw * inv;
        __builtin_nontemporal_store(o, (floatx4*)&out[(size_t)n * C + hl * 4]);
    }
}

// ---------------------------------------------------------------------------
extern "C" void kernel_launch(void* const* d_in, const int* in_sizes, int n_in,
                              void* d_out, int out_size, void* d_ws, size_t ws_size,
                              hipStream_t stream)
{
    const float* feat    = (const float*)d_in[0];
    const float* W       = (const float*)d_in[1];
    const float* att_src = (const float*)d_in[2];
    const float* att_dst = (const float*)d_in[3];
    const float* W_res   = (const float*)d_in[4];
    const int*   src     = (const int*)d_in[5];
    const int*   dst     = (const int*)d_in[6];
    float* out = (float*)d_out;

    char* p = (char*)d_ws;
    unsigned short* xb   = (unsigned short*)p; p += (size_t)NN * C * sizeof(unsigned short);
    unsigned short* resb = (unsigned short*)p; p += (size_t)NN * C * sizeof(unsigned short);
    unsigned short* Btf  = (unsigned short*)p; p += (size_t)256 * 128 * sizeof(unsigned short);
    float* a_s = (float*)p;            p += (size_t)NN * 4 * sizeof(float);
    float* a_d = (float*)p;            p += (size_t)NN * 4 * sizeof(float);
    int* deg     = (int*)p;            p += (size_t)NN * sizeof(int);
    int* row_ptr = (int*)p;            p += (size_t)(NN + 1) * sizeof(int);
    int* bsum    = (int*)p;            p += (size_t)256 * sizeof(int);
    int* rank    = (int*)p;            p += (size_t)NE * sizeof(int);
    int* csr_src = (int*)p;            p += (size_t)NE * sizeof(int);

    hipMemsetAsync(deg, 0, (size_t)NN * sizeof(int), stream);

    wconv_kernel<<<16, 256, 0, stream>>>(W, W_res, Btf);
    proj_hist_kernel<<<PROJ_NB + HIST_NB, 256, 0, stream>>>(
        feat, Btf, att_src, att_dst, dst, xb, resb, a_s, a_d, deg, rank);
    scan1_kernel<<<SCAN_NB, 1024, 0, stream>>>(deg, row_ptr, bsum);
    scan2_kernel<<<1, 128, 0, stream>>>(bsum);
    scan3_kernel<<<SCAN_NB, 1024, 0, stream>>>(row_ptr, bsum);
    scatter_kernel<<<(NE + 255) / 256, 256, 0, stream>>>(src, dst, rank, row_ptr, csr_src);
    agg_kernel<<<(NN + 3) / 4, 256, 0, stream>>>(xb, resb, a_s, a_d, row_ptr, csr_src, out);
}

// Round 8
// 332.431 us; speedup vs baseline: 1.2530x; 1.2530x over previous
//
#include <hip/hip_runtime.h>
#include <math.h>

#define NN 100000
#define NE 1600000
#define F_IN 128
#define C 128           // N_HEADS * F_OUT
#define NEG_SLOPE 0.2f
#define SCAN_NB ((NN + 1023) / 1024)   // 98
#define PROJ_NB ((NN + 63) / 64)       // 1563
#define HIST_NB ((NE + 255) / 256)     // 6250

typedef __attribute__((ext_vector_type(8))) short short8;    // 8 x bf16
typedef __attribute__((ext_vector_type(4))) float f32x4;
typedef __attribute__((ext_vector_type(4))) float floatx4;
typedef __attribute__((ext_vector_type(4))) unsigned short ushortx4;

static __device__ __forceinline__ unsigned short f2bf(float f) {
    unsigned int u = __float_as_uint(f);
    unsigned int r = (u + 0x7fff + ((u >> 16) & 1)) >> 16;  // RNE
    return (unsigned short)r;
}
static __device__ __forceinline__ float bf2f(unsigned short h) {
    return __uint_as_float((unsigned int)h << 16);
}

// ---------------------------------------------------------------------------
// Btf: fragment-major B for mfma_f32_16x16x32_bf16.
// Btf[((nt*4+kc)*64 + lane)*8 + j] = B[k][n], n = nt*16+(lane&15),
//   k = kc*32 + (lane>>4)*8 + j.  n<128 -> W, else W_res.
// ---------------------------------------------------------------------------
__global__ __launch_bounds__(256)
void wconv_kernel(const float* __restrict__ W,
                  const float* __restrict__ Wr,
                  unsigned short* __restrict__ Btf)
{
    int g = blockIdx.x * 256 + threadIdx.x;   // 0..4095
    int nt = g >> 8;
    int kc = (g >> 6) & 3;
    int l  = g & 63;
    int n  = nt * 16 + (l & 15);
    int kb = kc * 32 + (l >> 4) * 8;
    unsigned short v[8];
    #pragma unroll
    for (int j = 0; j < 8; ++j) {
        int k = kb + j;
        float f = (n < 128) ? W[(size_t)k * 128 + n] : Wr[(size_t)k * 128 + (n - 128)];
        v[j] = f2bf(f);
    }
    *(short8*)&Btf[(size_t)g * 8] = *(short8*)v;
}

// ---------------------------------------------------------------------------
// Fat kernel: blocks [0,PROJ_NB) = projection GEMM; blocks >= PROJ_NB = hist.
// proj: x(bf16)->xb, res(bf16)->resb, logits via LDS-staged coalesced store.
// B staged in LDS in two 32KB halves (once per block, shared by all 4 waves):
// kills the 400MB logical per-wave Btf stream that thrashed L1/L2.
// ---------------------------------------------------------------------------
__global__ __launch_bounds__(256)
void proj_hist_kernel(const float* __restrict__ feat,
                      const unsigned short* __restrict__ Btf,
                      const float* __restrict__ att_src,
                      const float* __restrict__ att_dst,
                      const int* __restrict__ dst,
                      unsigned short* __restrict__ xb,
                      unsigned short* __restrict__ resb,
                      float* __restrict__ a_s,
                      float* __restrict__ a_d,
                      int* __restrict__ deg,
                      int* __restrict__ rank)
{
    __shared__ __align__(16) char smem[17408];        // As / per-wave T2 overlay
    __shared__ __align__(16) unsigned short Bs[16384]; // 32KB: half of Btf
    __shared__ float s_as[64][4];
    __shared__ float s_ad[64][4];
    const int tid = threadIdx.x;

    if (blockIdx.x >= PROJ_NB) {          // ---- histogram part ----
        int e = (blockIdx.x - PROJ_NB) * 256 + tid;
        if (e < NE) rank[e] = atomicAdd(&deg[dst[e]], 1);
        return;
    }

    unsigned short* As = (unsigned short*)smem;   // [64][136]
    const int base = blockIdx.x * 64;

    // stage A: 64 rows x 128 cols fp32 -> bf16 LDS (nt loads: read-once)
    #pragma unroll
    for (int it = 0; it < 8; ++it) {
        int idx = it * 256 + tid;
        int row = idx >> 5;
        int c4  = idx & 31;
        int n = base + row;
        if (n < NN) {
            floatx4 f = __builtin_nontemporal_load(
                (const floatx4*)&feat[(size_t)n * F_IN + c4 * 4]);
            ushortx4 h;
            h.x = f2bf(f.x); h.y = f2bf(f.y); h.z = f2bf(f.z); h.w = f2bf(f.w);
            *(ushortx4*)&As[row * 136 + c4 * 4] = h;
        }
    }
    // stage B half 0 (nt 0..7): 2048 x 16B coalesced
    #pragma unroll
    for (int it = 0; it < 8; ++it) {
        int idx = it * 256 + tid;
        *(short8*)&Bs[idx * 8] = *(const short8*)&Btf[idx * 8];
    }
    __syncthreads();

    const int l = tid & 63;
    const int w = tid >> 6;
    const int quad = l >> 4;
    const int lo16 = l & 15;

    short8 af[4];
    const int arow = w * 16 + lo16;
    #pragma unroll
    for (int kc = 0; kc < 4; ++kc)
        af[kc] = *(const short8*)&As[arow * 136 + kc * 32 + quad * 8];

    f32x4 acc[16];
    #pragma unroll
    for (int nt = 0; nt < 16; ++nt) acc[nt] = (f32x4){0.f, 0.f, 0.f, 0.f};

    #pragma unroll
    for (int nt = 0; nt < 8; ++nt) {
        const unsigned short* bp = &Bs[(nt * 4) * 512 + l * 8];
        short8 b0 = *(const short8*)&bp[0];
        short8 b1 = *(const short8*)&bp[512];
        short8 b2 = *(const short8*)&bp[1024];
        short8 b3 = *(const short8*)&bp[1536];
        acc[nt] = __builtin_amdgcn_mfma_f32_16x16x32_bf16(af[0], b0, acc[nt], 0, 0, 0);
        acc[nt] = __builtin_amdgcn_mfma_f32_16x16x32_bf16(af[1], b1, acc[nt], 0, 0, 0);
        acc[nt] = __builtin_amdgcn_mfma_f32_16x16x32_bf16(af[2], b2, acc[nt], 0, 0, 0);
        acc[nt] = __builtin_amdgcn_mfma_f32_16x16x32_bf16(af[3], b3, acc[nt], 0, 0, 0);
    }

    __syncthreads();
    // stage B half 1 (nt 8..15)
    #pragma unroll
    for (int it = 0; it < 8; ++it) {
        int idx = it * 256 + tid;
        *(short8*)&Bs[idx * 8] = *(const short8*)&Btf[16384 + idx * 8];
    }
    __syncthreads();

    #pragma unroll
    for (int nt = 8; nt < 16; ++nt) {
        const unsigned short* bp = &Bs[((nt - 8) * 4) * 512 + l * 8];
        short8 b0 = *(const short8*)&bp[0];
        short8 b1 = *(const short8*)&bp[512];
        short8 b2 = *(const short8*)&bp[1024];
        short8 b3 = *(const short8*)&bp[1536];
        acc[nt] = __builtin_amdgcn_mfma_f32_16x16x32_bf16(af[0], b0, acc[nt], 0, 0, 0);
        acc[nt] = __builtin_amdgcn_mfma_f32_16x16x32_bf16(af[1], b1, acc[nt], 0, 0, 0);
        acc[nt] = __builtin_amdgcn_mfma_f32_16x16x32_bf16(af[2], b2, acc[nt], 0, 0, 0);
        acc[nt] = __builtin_amdgcn_mfma_f32_16x16x32_bf16(af[3], b3, acc[nt], 0, 0, 0);
    }

    float* T2 = (float*)smem + w * (16 * 68);   // wave-private [16][68]
    const int g  = l >> 4;          // row group within half-tile read
    const int cf = (l & 15) * 4;    // col within 64-col half

    // ---- x passes (nt 0..7) + logits to LDS ----
    #pragma unroll
    for (int p = 0; p < 2; ++p) {
        #pragma unroll
        for (int ntl = 0; ntl < 4; ++ntl) {
            int nt = p * 4 + ntl;
            #pragma unroll
            for (int r = 0; r < 4; ++r)
                T2[(quad * 4 + r) * 68 + ntl * 16 + lo16] = acc[nt][r];
        }
        floatx4 ws4 = *(const floatx4*)&att_src[p * 64 + cf];
        floatx4 wd4 = *(const floatx4*)&att_dst[p * 64 + cf];
        float ps[4], pd[4];
        #pragma unroll
        for (int it = 0; it < 4; ++it) {
            int row = it * 4 + g;
            floatx4 v = *(floatx4*)&T2[row * 68 + cf];
            int node = base + w * 16 + row;
            ushortx4 hh;
            hh.x = f2bf(v.x); hh.y = f2bf(v.y); hh.z = f2bf(v.z); hh.w = f2bf(v.w);
            if (node < NN)
                __builtin_nontemporal_store(hh,
                    (ushortx4*)&xb[(size_t)node * C + p * 64 + cf]);
            ps[it] = v.x * ws4.x + v.y * ws4.y + v.z * ws4.z + v.w * ws4.w;
            pd[it] = v.x * wd4.x + v.y * wd4.y + v.z * wd4.z + v.w * wd4.w;
        }
        #pragma unroll
        for (int it = 0; it < 4; ++it) {
            #pragma unroll
            for (int d = 1; d < 8; d <<= 1) {
                ps[it] += __shfl_xor(ps[it], d, 64);
                pd[it] += __shfl_xor(pd[it], d, 64);
            }
        }
        if ((l & 7) == 0) {
            int hh = p * 2 + ((l & 15) >> 3);
            #pragma unroll
            for (int it = 0; it < 4; ++it) {
                int lr = w * 16 + it * 4 + g;
                s_as[lr][hh] = ps[it];
                s_ad[lr][hh] = pd[it];
            }
        }
    }

    // ---- res passes (nt 8..15), bf16 -> resb ----
    #pragma unroll
    for (int p = 0; p < 2; ++p) {
        #pragma unroll
        for (int ntl = 0; ntl < 4; ++ntl) {
            int nt = 8 + p * 4 + ntl;
            #pragma unroll
            for (int r = 0; r < 4; ++r)
                T2[(quad * 4 + r) * 68 + ntl * 16 + lo16] = acc[nt][r];
        }
        #pragma unroll
        for (int it = 0; it < 4; ++it) {
            int row = it * 4 + g;
            floatx4 v = *(floatx4*)&T2[row * 68 + cf];
            int node = base + w * 16 + row;
            ushortx4 hh;
            hh.x = f2bf(v.x); hh.y = f2bf(v.y); hh.z = f2bf(v.z); hh.w = f2bf(v.w);
            if (node < NN)
                __builtin_nontemporal_store(hh,
                    (ushortx4*)&resb[(size_t)node * C + p * 64 + cf]);
        }
    }

    // ---- coalesced logits store: one contiguous 1KB store per array ----
    __syncthreads();
    int idx = blockIdx.x * 256 + tid;   // = base*4 + tid
    if (idx < NN * 4) {
        a_s[idx] = ((float*)s_as)[tid];
        a_d[idx] = ((float*)s_ad)[tid];
    }
}

// ---------------------------------------------------------------------------
// multi-block exclusive scan
// ---------------------------------------------------------------------------
__global__ __launch_bounds__(1024)
void scan1_kernel(const int* __restrict__ deg, int* __restrict__ row_ptr,
                  int* __restrict__ bsum)
{
    __shared__ int wsum[16];
    const int t = threadIdx.x, lane = t & 63, wid = t >> 6;
    const int i = blockIdx.x * 1024 + t;
    int v0 = (i < NN) ? deg[i] : 0;
    int v = v0;
    #pragma unroll
    for (int off = 1; off < 64; off <<= 1) {
        int u = __shfl_up(v, off, 64);
        if (lane >= off) v += u;
    }
    if (lane == 63) wsum[wid] = v;
    __syncthreads();
    if (t == 0) {
        int run = 0;
        #pragma unroll
        for (int s = 0; s < 16; ++s) { int tmp = wsum[s]; wsum[s] = run; run += tmp; }
        bsum[blockIdx.x] = run;
    }
    __syncthreads();
    if (i < NN) row_ptr[i] = wsum[wid] + (v - v0);
}

__global__ __launch_bounds__(128)
void scan2_kernel(int* __restrict__ bsum)
{
    __shared__ int w0;
    const int t = threadIdx.x, lane = t & 63;
    int v0 = (t < SCAN_NB) ? bsum[t] : 0;
    int v = v0;
    #pragma unroll
    for (int off = 1; off < 64; off <<= 1) {
        int u = __shfl_up(v, off, 64);
        if (lane >= off) v += u;
    }
    if (t == 63) w0 = v;
    __syncthreads();
    int excl = (v - v0) + ((t >= 64) ? w0 : 0);
    if (t < SCAN_NB) bsum[t] = excl;
}

__global__ __launch_bounds__(1024)
void scan3_kernel(int* __restrict__ row_ptr, const int* __restrict__ bsum)
{
    const int i = blockIdx.x * 1024 + threadIdx.x;
    if (i < NN) row_ptr[i] = row_ptr[i] + bsum[i >> 10];
    if (i == 0) row_ptr[NN] = NE;
}

// ---------------------------------------------------------------------------
// scatter: pure load->store, no atomics (plain store: let L2 write-combine)
// ---------------------------------------------------------------------------
__global__ void scatter_kernel(const int* __restrict__ src,
                               const int* __restrict__ dst,
                               const int* __restrict__ rank,
                               const int* __restrict__ row_ptr,
                               int* __restrict__ csr_src)
{
    int e = blockIdx.x * blockDim.x + threadIdx.x;
    if (e < NE)
        csr_src[row_ptr[dst[e]] + rank[e]] = src[e];
}

// ---------------------------------------------------------------------------
// aggregation: one wave per dst node, single pass.
// out = resb + acc/denom (no out read; contiguous nt store).
// ---------------------------------------------------------------------------
__global__ __launch_bounds__(256)
void agg_kernel(const unsigned short* __restrict__ xb,
                const unsigned short* __restrict__ resb,
                const float* __restrict__ a_s,
                const float* __restrict__ a_d,
                const int* __restrict__ row_ptr,
                const int* __restrict__ csr_src,
                float* __restrict__ out)
{
    __shared__ float s_alpha[4][64 * 4];
    __shared__ int   s_srcs[4][64];
    const int tid = threadIdx.x;
    const int w = tid >> 6;
    const int l = tid & 63;
    const int n = blockIdx.x * 4 + w;
    if (n >= NN) return;
    const int r0  = row_ptr[n];
    const int deg = row_ptr[n + 1] - r0;

    const int half = l >> 5;
    const int hl   = l & 31;
    const int h    = hl >> 3;

    if (deg == 0) {                      // out = residual only
        if (half == 0) {
            ushort4 rv = *(const ushort4*)&resb[(size_t)n * C + hl * 4];
            floatx4 o;
            o.x = bf2f(rv.x); o.y = bf2f(rv.y);
            o.z = bf2f(rv.z); o.w = bf2f(rv.w);
            __builtin_nontemporal_store(o, (floatx4*)&out[(size_t)n * C + hl * 4]);
        }
        return;
    }

    const float4 ad4 = *(const float4*)&a_d[n * 4];

    float ax = 0.f, ay = 0.f, az = 0.f, aw = 0.f;
    float dx = 0.f, dy = 0.f, dz = 0.f, dw = 0.f;

    for (int c0 = 0; c0 < deg; c0 += 64) {
        int e = c0 + l;
        int s = 0;
        float4 ex = {0.f, 0.f, 0.f, 0.f};
        if (e < deg) {
            s = csr_src[r0 + e];
            float4 as4 = *(const float4*)&a_s[s * 4];
            float e0 = as4.x + ad4.x, e1 = as4.y + ad4.y;
            float e2 = as4.z + ad4.z, e3 = as4.w + ad4.w;
            e0 = (e0 > 0.f) ? e0 : NEG_SLOPE * e0;
            e1 = (e1 > 0.f) ? e1 : NEG_SLOPE * e1;
            e2 = (e2 > 0.f) ? e2 : NEG_SLOPE * e2;
            e3 = (e3 > 0.f) ? e3 : NEG_SLOPE * e3;
            ex.x = __expf(e0); ex.y = __expf(e1);
            ex.z = __expf(e2); ex.w = __expf(e3);
            dx += ex.x; dy += ex.y; dz += ex.z; dw += ex.w;
        }
        s_srcs[w][l] = s;
        *(float4*)&s_alpha[w][l * 4] = ex;   // wave-private; DS in-order

        int cn = min(64, deg - c0);
        int iters = (cn + 1) >> 1;
        #pragma unroll 2
        for (int i = 0; i < iters; ++i) {
            int ii = i * 2 + half;
            int   si = s_srcs[w][ii];
            float al = s_alpha[w][ii * 4 + h];
            ushort4 uv = *(const ushort4*)&xb[(size_t)si * C + hl * 4];
            ax = fmaf(al, bf2f(uv.x), ax);
            ay = fmaf(al, bf2f(uv.y), ay);
            az = fmaf(al, bf2f(uv.z), az);
            aw = fmaf(al, bf2f(uv.w), aw);
        }
    }

    #pragma unroll
    for (int d = 32; d > 0; d >>= 1) {
        dx += __shfl_xor(dx, d, 64);
        dy += __shfl_xor(dy, d, 64);
        dz += __shfl_xor(dz, d, 64);
        dw += __shfl_xor(dw, d, 64);
    }
    float den = (h == 0) ? dx : (h == 1) ? dy : (h == 2) ? dz : dw;
    float inv = 1.f / den;

    ax += __shfl_xor(ax, 32, 64);
    ay += __shfl_xor(ay, 32, 64);
    az += __shfl_xor(az, 32, 64);
    aw += __shfl_xor(aw, 32, 64);

    if (half == 0) {
        ushort4 rv = *(const ushort4*)&resb[(size_t)n * C + hl * 4];
        floatx4 o;
        o.x = bf2f(rv.x) + ax * inv;
        o.y = bf2f(rv.y) + ay * inv;
        o.z = bf2f(rv.z) + az * inv;
        o.w = bf2f(rv.w) + aw * inv;
        __builtin_nontemporal_store(o, (floatx4*)&out[(size_t)n * C + hl * 4]);
    }
}

// ---------------------------------------------------------------------------
extern "C" void kernel_launch(void* const* d_in, const int* in_sizes, int n_in,
                              void* d_out, int out_size, void* d_ws, size_t ws_size,
                              hipStream_t stream)
{
    const float* feat    = (const float*)d_in[0];
    const float* W       = (const float*)d_in[1];
    const float* att_src = (const float*)d_in[2];
    const float* att_dst = (const float*)d_in[3];
    const float* W_res   = (const float*)d_in[4];
    const int*   src     = (const int*)d_in[5];
    const int*   dst     = (const int*)d_in[6];
    float* out = (float*)d_out;

    char* p = (char*)d_ws;
    unsigned short* xb   = (unsigned short*)p; p += (size_t)NN * C * sizeof(unsigned short);
    unsigned short* resb = (unsigned short*)p; p += (size_t)NN * C * sizeof(unsigned short);
    unsigned short* Btf  = (unsigned short*)p; p += (size_t)256 * 128 * sizeof(unsigned short);
    float* a_s = (float*)p;            p += (size_t)NN * 4 * sizeof(float);
    float* a_d = (float*)p;            p += (size_t)NN * 4 * sizeof(float);
    int* deg     = (int*)p;            p += (size_t)NN * sizeof(int);
    int* row_ptr = (int*)p;            p += (size_t)(NN + 1) * sizeof(int);
    int* bsum    = (int*)p;            p += (size_t)256 * sizeof(int);
    int* rank    = (int*)p;            p += (size_t)NE * sizeof(int);
    int* csr_src = (int*)p;            p += (size_t)NE * sizeof(int);

    hipMemsetAsync(deg, 0, (size_t)NN * sizeof(int), stream);

    wconv_kernel<<<16, 256, 0, stream>>>(W, W_res, Btf);
    proj_hist_kernel<<<PROJ_NB + HIST_NB, 256, 0, stream>>>(
        feat, Btf, att_src, att_dst, dst, xb, resb, a_s, a_d, deg, rank);
    scan1_kernel<<<SCAN_NB, 1024, 0, stream>>>(deg, row_ptr, bsum);
    scan2_kernel<<<1, 128, 0, stream>>>(bsum);
    scan3_kernel<<<SCAN_NB, 1024, 0, stream>>>(row_ptr, bsum);
    scatter_kernel<<<(NE + 255) / 256, 256, 0, stream>>>(src, dst, rank, row_ptr, csr_src);
    agg_kernel<<<(NN + 3) / 4, 256, 0, stream>>>(xb, resb, a_s, a_d, row_ptr, csr_src, out);
}